// Round 2
// baseline (302.122 us; speedup 1.0000x reference)
//
#include <hip/hip_runtime.h>
#include <hip/hip_bf16.h>

typedef unsigned short u16;
typedef unsigned int u32;
typedef __attribute__((ext_vector_type(8))) short short8;
typedef __attribute__((ext_vector_type(4))) float f32x4;

__device__ __forceinline__ u16 f2bf(float f) {
    union { float f; u32 u; } c; c.f = f;
    u32 u = c.u;
    return (u16)((u + 0x7fffu + ((u >> 16) & 1u)) >> 16);
}

#define MFMA16(A, B, C) __builtin_amdgcn_mfma_f32_16x16x32_bf16((A), (B), (C), 0, 0, 0)

// ---------------------------------------------------------------------------
// Wire-format probe: inspect W1's first 1024 u16 words. If wire is bf16, the
// exponent field of nearly every word is in a sane range for N(0, 0.0099)
// data. If wire is fp32, even-indexed words are low mantissa halves with
// uniform-random exponent fields (~12.5% sane) -> total ~56% sane.
// flag = 0 -> bf16 wire, 1 -> fp32 wire.
// ---------------------------------------------------------------------------
__global__ void probe_dtype(const u16* __restrict__ w1, u32* __restrict__ flag) {
    int lane = threadIdx.x;  // 64 threads, 1 block
    int cnt = 0;
    #pragma unroll
    for (int j = 0; j < 16; ++j) {
        u16 v = w1[lane * 16 + j];
        u32 E = (v >> 7) & 0xFF;
        if (v == 0 || (E >= 0x60 && E < 0x80)) cnt++;
    }
    #pragma unroll
    for (int off = 32; off; off >>= 1) cnt += __shfl_down(cnt, off, 64);
    if (lane == 0) *flag = (cnt >= 820) ? 0u : 1u;
}

// dtype-polymorphic element / 8-vector loads (result: bf16 bit patterns)
template <bool F32>
__device__ __forceinline__ short ldw(const void* p, int i) {
    if constexpr (F32) return (short)f2bf(((const float*)p)[i]);
    else               return ((const short*)p)[i];
}

template <bool F32>
__device__ __forceinline__ short8 ld8(const void* p, long i) {
    short8 r;
    if constexpr (F32) {
        const float4* q = (const float4*)((const float*)p + i);
        float4 a = q[0], b = q[1];
        r[0] = (short)f2bf(a.x); r[1] = (short)f2bf(a.y);
        r[2] = (short)f2bf(a.z); r[3] = (short)f2bf(a.w);
        r[4] = (short)f2bf(b.x); r[5] = (short)f2bf(b.y);
        r[6] = (short)f2bf(b.z); r[7] = (short)f2bf(b.w);
    } else {
        r = *(const short8*)((const u16*)p + i);
    }
    return r;
}

// ---------------------------------------------------------------------------
// Fused BTT, no workspace. Natural layouts:
//   x  : (4096, 4096)        x[b][m2*64+m1]
//   W1 : (64, 64, 256)       W1[m2][m1][c],   c = n1*4 + r
//   W2 : (64, 256, 64)       W2[n1][k][n2],   k = m2*4 + r
// WG: 512 thr = 8 waves. Tile: 64 batch rows (bt), 8 n1 (nb). Per m2-block
// iteration, wave w computes stage-1 t[b][m2=m2b*8+w][c' in nb*32+[0,32)]
// into LDS, then stage-2 for n1 = nb*8+w accumulates y (64x64/wave) in AGPRs.
// MFMA 16x16x32 bf16: A[m=lane&15][k=q*8+j], B[k=q*8+j][n=lane&15],
//                     D[row=q*4+reg][col=lane&15].
// ---------------------------------------------------------------------------
template <bool F32>
__device__ __forceinline__ void btt_body(const void* __restrict__ x,
                                         const void* __restrict__ W1,
                                         const void* __restrict__ W2,
                                         void* __restrict__ out,
                                         u16* __restrict__ t_lds) {
    const int tid = threadIdx.x;
    const int w = tid >> 6;       // wave 0..7
    const int lane = tid & 63;
    const int q = lane >> 4;      // quad
    const int lr = lane & 15;
    const int bt = blockIdx.x & 63;
    const int nb = blockIdx.x >> 6;
    const int n1 = nb * 8 + w;

    const f32x4 fz = {0.f, 0.f, 0.f, 0.f};
    f32x4 acc2[4][4];
    #pragma unroll
    for (int i = 0; i < 4; ++i)
        #pragma unroll
        for (int j = 0; j < 4; ++j) acc2[i][j] = fz;

    for (int m2b = 0; m2b < 8; ++m2b) {
        const int m2 = m2b * 8 + w;

        // ---- stage 1: t[b][c'] = x_slice(b x m1) . W1_slice(m1 x c') ----
        // A = x: m = b = bl*16+lr, k = m1 = ks*32+q*8+j  (vectorized, natural)
        short8 ax[4][2];
        #pragma unroll
        for (int bl = 0; bl < 4; ++bl)
            #pragma unroll
            for (int ks = 0; ks < 2; ++ks)
                ax[bl][ks] = ld8<F32>(x, (long)(bt * 64 + bl * 16 + lr) * 4096 +
                                             m2 * 64 + ks * 32 + q * 8);
        // B = W1: k = m1 = ks*32+q*8+j, n = c' = ct*16+lr (strided scalar)
        short8 bw1[2][2];
        #pragma unroll
        for (int ct = 0; ct < 2; ++ct)
            #pragma unroll
            for (int ks = 0; ks < 2; ++ks)
                #pragma unroll
                for (int j = 0; j < 8; ++j)
                    bw1[ct][ks][j] = ldw<F32>(W1, m2 * 16384 +
                                                  (ks * 32 + q * 8 + j) * 256 +
                                                  nb * 32 + ct * 16 + lr);
        f32x4 acc1[4][2];
        #pragma unroll
        for (int bl = 0; bl < 4; ++bl)
            #pragma unroll
            for (int ct = 0; ct < 2; ++ct) acc1[bl][ct] = fz;
        #pragma unroll
        for (int ks = 0; ks < 2; ++ks)
            #pragma unroll
            for (int bl = 0; bl < 4; ++bl)
                #pragma unroll
                for (int ct = 0; ct < 2; ++ct)
                    acc1[bl][ct] = MFMA16(ax[bl][ks], bw1[ct][ks], acc1[bl][ct]);

        __syncthreads();  // prior iteration's stage-2 LDS reads done

        // D[m=b][n=c']: b = bl*16 + q*4 + g, c' = ct*16 + lr
        // t_lds[b][w*32 + c']  (row stride 260)
        #pragma unroll
        for (int bl = 0; bl < 4; ++bl)
            #pragma unroll
            for (int ct = 0; ct < 2; ++ct)
                #pragma unroll
                for (int g = 0; g < 4; ++g)
                    t_lds[(bl * 16 + q * 4 + g) * 260 + w * 32 + ct * 16 + lr] =
                        f2bf(acc1[bl][ct][g]);

        __syncthreads();  // all t written

        // ---- stage 2: y[b][n2] += t2(64x32) . W2_slice(32x64) ----
        // A2: m = b = bl*16+lr, k2 = q*8+j = m2l*4+r
        //   j=0..3 -> slot 2q, r=j; j=4..7 -> slot 2q+1, r=j-4
        short8 a2[4];
        #pragma unroll
        for (int bl = 0; bl < 4; ++bl) {
            int base = (bl * 16 + lr) * 260 + (2 * q) * 32 + w * 4;
            union { short8 v; uint2 u[2]; } tmp;
            tmp.u[0] = *(const uint2*)(&t_lds[base]);
            tmp.u[1] = *(const uint2*)(&t_lds[base + 32]);
            a2[bl] = tmp.v;
        }
        // B2 = W2: k = m2b*32 + q*8 + j, n2 = nt*16 + lr (strided scalar)
        short8 b2[4];
        #pragma unroll
        for (int nt = 0; nt < 4; ++nt)
            #pragma unroll
            for (int j = 0; j < 8; ++j)
                b2[nt][j] = ldw<F32>(W2, n1 * 16384 +
                                         (m2b * 32 + q * 8 + j) * 64 +
                                         nt * 16 + lr);
        #pragma unroll
        for (int bl = 0; bl < 4; ++bl)
            #pragma unroll
            for (int nt = 0; nt < 4; ++nt)
                acc2[bl][nt] = MFMA16(a2[bl], b2[nt], acc2[bl][nt]);
    }

    // ---- epilogue: D rows = b (q*4+g), cols = n2 (lr) ----
    #pragma unroll
    for (int bl = 0; bl < 4; ++bl)
        #pragma unroll
        for (int nt = 0; nt < 4; ++nt)
            #pragma unroll
            for (int g = 0; g < 4; ++g) {
                long row = bt * 64 + bl * 16 + q * 4 + g;
                long col = (long)n1 * 64 + nt * 16 + lr;
                if constexpr (F32)
                    ((float*)out)[row * 4096 + col] = acc2[bl][nt][g];
                else
                    ((u16*)out)[row * 4096 + col] = f2bf(acc2[bl][nt][g]);
            }
}

__global__ __launch_bounds__(512) void btt_main(const void* __restrict__ x,
                                                const void* __restrict__ W1,
                                                const void* __restrict__ W2,
                                                void* __restrict__ out,
                                                const u32* __restrict__ flag) {
    __shared__ u16 t_lds[64 * 260];
    if (*flag)
        btt_body<true>(x, W1, W2, out, t_lds);
    else
        btt_body<false>(x, W1, W2, out, t_lds);
}

extern "C" void kernel_launch(void* const* d_in, const int* in_sizes, int n_in,
                              void* d_out, int out_size, void* d_ws, size_t ws_size,
                              hipStream_t stream) {
    const void* x  = d_in[0];   // (4096, 4096)
    const void* W1 = d_in[1];   // (64, 64, 256)
    const void* W2 = d_in[2];   // (64, 256, 64)
    u32* flag = (u32*)d_ws;     // 4 bytes only

    probe_dtype<<<1, 64, 0, stream>>>((const u16*)W1, flag);
    btt_main<<<512, 512, 0, stream>>>(x, W1, W2, d_out, flag);
}

// Round 3
// 243.115 us; speedup vs baseline: 1.2427x; 1.2427x over previous
//
#include <hip/hip_runtime.h>

typedef unsigned short u16;
typedef unsigned int u32;
typedef __attribute__((ext_vector_type(8))) short short8;
typedef __attribute__((ext_vector_type(4))) float f32x4;

__device__ __forceinline__ u16 f2bf(float f) {
    union { float f; u32 u; } c; c.f = f;
    u32 u = c.u;
    return (u16)((u + 0x7fffu + ((u >> 16) & 1u)) >> 16);
}

#define MFMA16(A, B, C) __builtin_amdgcn_mfma_f32_16x16x32_bf16((A), (B), (C), 0, 0, 0)

// ---------------------------------------------------------------------------
// Transpose + fp32->bf16 convert: per batch, in is ROWS x COLS fp32 (row-major),
// out is COLS x ROWS bf16. One block per batch, 256 threads. ROWS*COLS = 16384.
// ---------------------------------------------------------------------------
template <int ROWS, int COLS>
__global__ __launch_bounds__(256) void transpose_cvt(const float* __restrict__ in,
                                                     u16* __restrict__ out) {
    __shared__ u16 lds[ROWS][COLS + 8];
    const float* src = in + (size_t)blockIdx.x * (ROWS * COLS);
    u16* dst = out + (size_t)blockIdx.x * (ROWS * COLS);
    const int t = threadIdx.x;

    #pragma unroll
    for (int v = 0; v < 8; ++v) {                 // 8 * 256 * 8 = 16384 elems
        int flat = v * 2048 + t * 8;
        float4 a = *(const float4*)(src + flat);
        float4 b = *(const float4*)(src + flat + 4);
        int r = flat / COLS, c = flat % COLS;     // 8 | COLS -> no row crossing
        lds[r][c + 0] = f2bf(a.x); lds[r][c + 1] = f2bf(a.y);
        lds[r][c + 2] = f2bf(a.z); lds[r][c + 3] = f2bf(a.w);
        lds[r][c + 4] = f2bf(b.x); lds[r][c + 5] = f2bf(b.y);
        lds[r][c + 6] = f2bf(b.z); lds[r][c + 7] = f2bf(b.w);
    }
    __syncthreads();
    #pragma unroll
    for (int v = 0; v < 8; ++v) {
        int flat = v * 2048 + t * 8;              // out flat = c * ROWS + r
        int c = flat / ROWS, r0 = flat % ROWS;    // 8 | ROWS -> no col crossing
        short8 val;
        #pragma unroll
        for (int j = 0; j < 8; ++j) val[j] = (short)lds[r0 + j][c];
        *(short8*)(dst + flat) = val;
    }
}

// ---------------------------------------------------------------------------
// Fused BTT main kernel (fp32 x / fp32 out wire, bf16 MFMA math).
//   x   : (4096, 4096) fp32         x[b][m2*64+m1]
//   W1T : (m2=64, c=256, m1=64) bf16  (c = n1*4 + r, k=m1 contiguous)
//   W2T : (n1=64, n2=64, k=256) bf16  (k = m2*4 + r contiguous)
//   out : (4096, 4096) fp32
// WG: 512 thr = 8 waves. Tile: 64 batch rows (bt) x 8 n1 (nb). Per m2-block
// iteration, wave w runs stage-1 for m2 = m2b*8+w producing tT[c'(32)][b(64)]
// into LDS (t_lds[b][w][c'], row stride 260), then stage-2 for n1 = nb*8+w
// accumulating y (64x64 per wave) in AGPRs.
// MFMA 16x16x32 bf16: A[m=lane&15][k=q*8+j], B[k=q*8+j][n=lane&15],
//                     D[row=q*4+reg][col=lane&15]  (m89/m91-verified).
// ---------------------------------------------------------------------------
__global__ __launch_bounds__(512) void btt_main(const float* __restrict__ x,
                                                const u16* __restrict__ W1T,
                                                const u16* __restrict__ W2T,
                                                float* __restrict__ out) {
    __shared__ u16 t_lds[64 * 260];

    const int tid = threadIdx.x;
    const int w = tid >> 6;       // wave 0..7
    const int lane = tid & 63;
    const int q = lane >> 4;      // quad
    const int lr = lane & 15;
    const int nb = blockIdx.x & 7;   // consecutive blocks share bt -> x L2 reuse
    const int bt = blockIdx.x >> 3;
    const int n1 = nb * 8 + w;

    const f32x4 fz = {0.f, 0.f, 0.f, 0.f};
    f32x4 acc2[4][4];             // y[b(4x16)][n2(4x16)]
    #pragma unroll
    for (int i = 0; i < 4; ++i)
        #pragma unroll
        for (int j = 0; j < 4; ++j) acc2[i][j] = fz;

    for (int m2b = 0; m2b < 8; ++m2b) {
        const int m2 = m2b * 8 + w;

        // ---- stage 1: tT[c'(32)][b(64)] = W1T_slice(32x64) . xT(64x64) ----
        // A = W1T: m = c' = ct*16+lr, k = m1 = ks*32+q*8+j (16B bf16 loads)
        short8 a1[2][2];
        {
            const u16* w1p = W1T + m2 * 16384 + (nb * 32 + lr) * 64 + q * 8;
            #pragma unroll
            for (int ct = 0; ct < 2; ++ct)
                #pragma unroll
                for (int ks = 0; ks < 2; ++ks)
                    a1[ct][ks] = *(const short8*)(w1p + ct * (16 * 64) + ks * 32);
        }
        // B = x^T: k = m1 = ks*32+q*8+j, n = b = bl*16+lr (fp32 -> bf16)
        short8 b1[4][2];
        {
            const float* xp = x + (size_t)(bt * 64 + lr) * 4096 + m2 * 64 + q * 8;
            #pragma unroll
            for (int bl = 0; bl < 4; ++bl)
                #pragma unroll
                for (int ks = 0; ks < 2; ++ks) {
                    const float* p = xp + bl * 16 * 4096 + ks * 32;
                    float4 ua = *(const float4*)(p);
                    float4 ub = *(const float4*)(p + 4);
                    short8 r;
                    r[0] = (short)f2bf(ua.x); r[1] = (short)f2bf(ua.y);
                    r[2] = (short)f2bf(ua.z); r[3] = (short)f2bf(ua.w);
                    r[4] = (short)f2bf(ub.x); r[5] = (short)f2bf(ub.y);
                    r[6] = (short)f2bf(ub.z); r[7] = (short)f2bf(ub.w);
                    b1[bl][ks] = r;
                }
        }
        f32x4 acc1[2][4];
        #pragma unroll
        for (int ct = 0; ct < 2; ++ct)
            #pragma unroll
            for (int bl = 0; bl < 4; ++bl) acc1[ct][bl] = fz;
        #pragma unroll
        for (int ks = 0; ks < 2; ++ks)
            #pragma unroll
            for (int ct = 0; ct < 2; ++ct)
                #pragma unroll
                for (int bl = 0; bl < 4; ++bl)
                    acc1[ct][bl] = MFMA16(a1[ct][ks], b1[bl][ks], acc1[ct][bl]);

        __syncthreads();   // prior iteration's stage-2 LDS reads done

        // write tT -> t_lds[b][w*32 + c']; D: row = c' = ct*16+q*4+g, col = b = bl*16+lr
        #pragma unroll
        for (int ct = 0; ct < 2; ++ct)
            #pragma unroll
            for (int bl = 0; bl < 4; ++bl) {
                int off = (bl * 16 + lr) * 260 + w * 32 + ct * 16 + q * 4;
                u32 lo = (u32)f2bf(acc1[ct][bl][0]) | ((u32)f2bf(acc1[ct][bl][1]) << 16);
                u32 hi = (u32)f2bf(acc1[ct][bl][2]) | ((u32)f2bf(acc1[ct][bl][3]) << 16);
                *(uint2*)(&t_lds[off]) = make_uint2(lo, hi);
            }

        __syncthreads();   // all t written before stage-2 reads

        // ---- stage 2: y[b][n2] += t2(64x32) . W2T_slice(32x64) ----
        // A2: m = b = bl*16+lr, k2 = q*8+j = m2l*4+r  (HW-proven reader)
        short8 a2[4];
        #pragma unroll
        for (int bl = 0; bl < 4; ++bl) {
            int base = (bl * 16 + lr) * 260 + (2 * q) * 32 + w * 4;
            union { short8 v; uint2 u[2]; } tmp;
            tmp.u[0] = *(const uint2*)(&t_lds[base]);
            tmp.u[1] = *(const uint2*)(&t_lds[base + 32]);
            a2[bl] = tmp.v;
        }
        // B2 = W2T: k = m2b*32+q*8+j contiguous, n2 = nt*16+lr (16B bf16 loads)
        short8 b2[4];
        {
            const u16* w2p = W2T + n1 * 16384 + lr * 256 + m2b * 32 + q * 8;
            #pragma unroll
            for (int nt = 0; nt < 4; ++nt)
                b2[nt] = *(const short8*)(w2p + nt * (16 * 256));
        }
        #pragma unroll
        for (int bl = 0; bl < 4; ++bl)
            #pragma unroll
            for (int nt = 0; nt < 4; ++nt)
                acc2[bl][nt] = MFMA16(a2[bl], b2[nt], acc2[bl][nt]);
    }

    // ---- epilogue: D rows = b (q*4+g), cols = n2 (lr); fp32 stores ----
    #pragma unroll
    for (int bl = 0; bl < 4; ++bl)
        #pragma unroll
        for (int nt = 0; nt < 4; ++nt)
            #pragma unroll
            for (int g = 0; g < 4; ++g) {
                long row = bt * 64 + bl * 16 + q * 4 + g;
                long col = (long)n1 * 64 + nt * 16 + lr;
                out[row * 4096 + col] = acc2[bl][nt][g];
            }
}

// ---------------------------------------------------------------------------
// Fallback (no workspace): scalar weight loads straight from natural layouts.
// HW-proven in round 2 (fp32 path). Used only if ws_size < 4 MB.
// ---------------------------------------------------------------------------
__global__ __launch_bounds__(512) void btt_nows(const float* __restrict__ x,
                                                const float* __restrict__ W1,
                                                const float* __restrict__ W2,
                                                float* __restrict__ out) {
    __shared__ u16 t_lds[64 * 260];
    const int tid = threadIdx.x;
    const int w = tid >> 6;
    const int lane = tid & 63;
    const int q = lane >> 4;
    const int lr = lane & 15;
    const int nb = blockIdx.x & 7;
    const int bt = blockIdx.x >> 3;
    const int n1 = nb * 8 + w;

    const f32x4 fz = {0.f, 0.f, 0.f, 0.f};
    f32x4 acc2[4][4];
    #pragma unroll
    for (int i = 0; i < 4; ++i)
        #pragma unroll
        for (int j = 0; j < 4; ++j) acc2[i][j] = fz;

    for (int m2b = 0; m2b < 8; ++m2b) {
        const int m2 = m2b * 8 + w;
        short8 ax[4][2];
        #pragma unroll
        for (int bl = 0; bl < 4; ++bl)
            #pragma unroll
            for (int ks = 0; ks < 2; ++ks) {
                const float* p = x + (size_t)(bt * 64 + bl * 16 + lr) * 4096 +
                                 m2 * 64 + ks * 32 + q * 8;
                float4 ua = *(const float4*)(p);
                float4 ub = *(const float4*)(p + 4);
                short8 r;
                r[0] = (short)f2bf(ua.x); r[1] = (short)f2bf(ua.y);
                r[2] = (short)f2bf(ua.z); r[3] = (short)f2bf(ua.w);
                r[4] = (short)f2bf(ub.x); r[5] = (short)f2bf(ub.y);
                r[6] = (short)f2bf(ub.z); r[7] = (short)f2bf(ub.w);
                ax[bl][ks] = r;
            }
        short8 bw1[2][2];
        #pragma unroll
        for (int ct = 0; ct < 2; ++ct)
            #pragma unroll
            for (int ks = 0; ks < 2; ++ks)
                #pragma unroll
                for (int j = 0; j < 8; ++j)
                    bw1[ct][ks][j] = (short)f2bf(W1[m2 * 16384 +
                                                    (ks * 32 + q * 8 + j) * 256 +
                                                    nb * 32 + ct * 16 + lr]);
        f32x4 acc1[4][2];
        #pragma unroll
        for (int bl = 0; bl < 4; ++bl)
            #pragma unroll
            for (int ct = 0; ct < 2; ++ct) acc1[bl][ct] = fz;
        #pragma unroll
        for (int ks = 0; ks < 2; ++ks)
            #pragma unroll
            for (int bl = 0; bl < 4; ++bl)
                #pragma unroll
                for (int ct = 0; ct < 2; ++ct)
                    acc1[bl][ct] = MFMA16(ax[bl][ks], bw1[ct][ks], acc1[bl][ct]);

        __syncthreads();
        #pragma unroll
        for (int bl = 0; bl < 4; ++bl)
            #pragma unroll
            for (int ct = 0; ct < 2; ++ct)
                #pragma unroll
                for (int g = 0; g < 4; ++g)
                    t_lds[(bl * 16 + q * 4 + g) * 260 + w * 32 + ct * 16 + lr] =
                        f2bf(acc1[bl][ct][g]);
        __syncthreads();

        short8 a2[4];
        #pragma unroll
        for (int bl = 0; bl < 4; ++bl) {
            int base = (bl * 16 + lr) * 260 + (2 * q) * 32 + w * 4;
            union { short8 v; uint2 u[2]; } tmp;
            tmp.u[0] = *(const uint2*)(&t_lds[base]);
            tmp.u[1] = *(const uint2*)(&t_lds[base + 32]);
            a2[bl] = tmp.v;
        }
        short8 b2[4];
        #pragma unroll
        for (int nt = 0; nt < 4; ++nt)
            #pragma unroll
            for (int j = 0; j < 8; ++j)
                b2[nt][j] = (short)f2bf(W2[n1 * 16384 +
                                           (m2b * 32 + q * 8 + j) * 64 +
                                           nt * 16 + lr]);
        #pragma unroll
        for (int bl = 0; bl < 4; ++bl)
            #pragma unroll
            for (int nt = 0; nt < 4; ++nt)
                acc2[bl][nt] = MFMA16(a2[bl], b2[nt], acc2[bl][nt]);
    }

    #pragma unroll
    for (int bl = 0; bl < 4; ++bl)
        #pragma unroll
        for (int nt = 0; nt < 4; ++nt)
            #pragma unroll
            for (int g = 0; g < 4; ++g) {
                long row = bt * 64 + bl * 16 + q * 4 + g;
                long col = (long)n1 * 64 + nt * 16 + lr;
                out[row * 4096 + col] = acc2[bl][nt][g];
            }
}

extern "C" void kernel_launch(void* const* d_in, const int* in_sizes, int n_in,
                              void* d_out, int out_size, void* d_ws, size_t ws_size,
                              hipStream_t stream) {
    const float* x  = (const float*)d_in[0];   // (4096, 4096) fp32
    const float* W1 = (const float*)d_in[1];   // (64, 64, 256) fp32
    const float* W2 = (const float*)d_in[2];   // (64, 256, 64) fp32
    float* out = (float*)d_out;

    const size_t WS_NEED = 2u * 64 * 256 * 64 * sizeof(u16);  // 4 MB
    if (ws_size >= WS_NEED) {
        u16* W1T = (u16*)d_ws;                 // (64, 256, 64) bf16, 2 MB
        u16* W2T = W1T + 64 * 256 * 64;        // (64, 64, 256) bf16, 2 MB
        transpose_cvt<64, 256><<<64, 256, 0, stream>>>(W1, W1T);  // (m1,c)->(c,m1)
        transpose_cvt<256, 64><<<64, 256, 0, stream>>>(W2, W2T);  // (k,n2)->(n2,k)
        btt_main<<<512, 512, 0, stream>>>(x, W1T, W2T, out);
    } else {
        btt_nows<<<512, 512, 0, stream>>>(x, (const float*)W1, (const float*)W2, out);
    }
}

// Round 4
// 194.093 us; speedup vs baseline: 1.5566x; 1.2526x over previous
//
#include <hip/hip_runtime.h>

typedef unsigned short u16;
typedef unsigned int u32;
typedef __attribute__((ext_vector_type(8))) short short8;
typedef __attribute__((ext_vector_type(4))) float f32x4;

__device__ __forceinline__ u16 f2bf(float f) {
    union { float f; u32 u; } c; c.f = f;
    u32 u = c.u;
    return (u16)((u + 0x7fffu + ((u >> 16) & 1u)) >> 16);
}

#define MFMA16(A, B, C) __builtin_amdgcn_mfma_f32_16x16x32_bf16((A), (B), (C), 0, 0, 0)

// ---------------------------------------------------------------------------
// x fp32 -> bf16 streaming convert. 8 elems/thread, fully coalesced.
// ---------------------------------------------------------------------------
__global__ __launch_bounds__(256) void cvt_x(const float* __restrict__ in,
                                             u16* __restrict__ out) {
    size_t i = ((size_t)blockIdx.x * 256 + threadIdx.x) * 8;
    float4 a = *(const float4*)(in + i);
    float4 b = *(const float4*)(in + i + 4);
    short8 r;
    r[0] = (short)f2bf(a.x); r[1] = (short)f2bf(a.y);
    r[2] = (short)f2bf(a.z); r[3] = (short)f2bf(a.w);
    r[4] = (short)f2bf(b.x); r[5] = (short)f2bf(b.y);
    r[6] = (short)f2bf(b.z); r[7] = (short)f2bf(b.w);
    *(short8*)(out + i) = r;
}

// ---------------------------------------------------------------------------
// Batched transpose + fp32->bf16: per batch, in ROWS x COLS fp32 -> out
// COLS x ROWS bf16. Each block handles RCHUNK input rows (all COLS);
// grid = batches * (ROWS/RCHUNK). LDS row stride COLS+6 (odd dword count)
// keeps the column-read conflicts <= 2-way. RCHUNK*COLS must be 4096.
// ---------------------------------------------------------------------------
template <int ROWS, int COLS, int RCHUNK>
__global__ __launch_bounds__(256) void transpose_cvt(const float* __restrict__ in,
                                                     u16* __restrict__ out) {
    constexpr int STRIDE = COLS + 6;
    constexpr int NCH = ROWS / RCHUNK;
    __shared__ u16 lds[RCHUNK][STRIDE];
    const int batch = blockIdx.x / NCH;
    const int r0 = (blockIdx.x % NCH) * RCHUNK;
    const float* src = in + (size_t)batch * ROWS * COLS + (size_t)r0 * COLS;
    u16* dst = out + (size_t)batch * ROWS * COLS;
    const int t = threadIdx.x;

    #pragma unroll
    for (int v = 0; v < 2; ++v) {                 // 2 * 256 * 8 = 4096 elems
        int flat = v * 2048 + t * 8;
        float4 a = *(const float4*)(src + flat);
        float4 b = *(const float4*)(src + flat + 4);
        int r = flat / COLS, c = flat % COLS;     // 8 | COLS -> no row crossing
        lds[r][c + 0] = f2bf(a.x); lds[r][c + 1] = f2bf(a.y);
        lds[r][c + 2] = f2bf(a.z); lds[r][c + 3] = f2bf(a.w);
        lds[r][c + 4] = f2bf(b.x); lds[r][c + 5] = f2bf(b.y);
        lds[r][c + 6] = f2bf(b.z); lds[r][c + 7] = f2bf(b.w);
    }
    __syncthreads();
    #pragma unroll
    for (int v = 0; v < 2; ++v) {
        int flat = v * 2048 + t * 8;
        int c = flat / RCHUNK, rl = flat % RCHUNK;  // 8 | RCHUNK
        short8 val;
        #pragma unroll
        for (int j = 0; j < 8; ++j) val[j] = (short)lds[rl + j][c];
        *(short8*)(dst + (size_t)c * ROWS + r0 + rl) = val;
    }
}

// ---------------------------------------------------------------------------
// Fused BTT main kernel (bf16 MFMA math, fp32 out wire).
//   x    : XBF ? (4096,4096) bf16 (pre-converted) : fp32
//   W1T  : (m2=64, c=256, m1=64) bf16   (c = n1*4 + r, k=m1 contiguous)
//   W2T  : (n1=64, n2=64, k=256) bf16   (k = m2*4 + r contiguous)
//   out  : (4096, 4096) fp32
// Block mapping bt = blockIdx&63, nb = blockIdx>>6: all 8 nb-blocks sharing
// an x-tile land on the same XCD (xcd = blockIdx%8 = bt%8) -> x-tile served
// from that XCD's L2 (round-2-measured: 98 MB fetch vs 300 MB flipped).
// MFMA 16x16x32 bf16: A[m=lane&15][k=q*8+j], B[k=q*8+j][n=lane&15],
//                     D[row=q*4+reg][col=lane&15]  (m89/m91-verified).
// ---------------------------------------------------------------------------
template <bool XBF>
__global__ __launch_bounds__(512) void btt_main(const void* __restrict__ x_,
                                                const u16* __restrict__ W1T,
                                                const u16* __restrict__ W2T,
                                                float* __restrict__ out) {
    __shared__ u16 t_lds[64 * 260];

    const int tid = threadIdx.x;
    const int w = tid >> 6;       // wave 0..7
    const int lane = tid & 63;
    const int q = lane >> 4;      // quad
    const int lr = lane & 15;
    const int bt = blockIdx.x & 63;
    const int nb = blockIdx.x >> 6;
    const int n1 = nb * 8 + w;

    const f32x4 fz = {0.f, 0.f, 0.f, 0.f};
    f32x4 acc2[4][4];             // y[b(4x16)][n2(4x16)]
    #pragma unroll
    for (int i = 0; i < 4; ++i)
        #pragma unroll
        for (int j = 0; j < 4; ++j) acc2[i][j] = fz;

    for (int m2b = 0; m2b < 8; ++m2b) {
        const int m2 = m2b * 8 + w;

        // ---- stage 1: tT[c'(32)][b(64)] = W1T_slice(32x64) . xT(64x64) ----
        // A = W1T: m = c' = ct*16+lr, k = m1 = ks*32+q*8+j (16B bf16 loads)
        short8 a1[2][2];
        {
            const u16* w1p = W1T + m2 * 16384 + (nb * 32 + lr) * 64 + q * 8;
            #pragma unroll
            for (int ct = 0; ct < 2; ++ct)
                #pragma unroll
                for (int ks = 0; ks < 2; ++ks)
                    a1[ct][ks] = *(const short8*)(w1p + ct * (16 * 64) + ks * 32);
        }
        // B = x^T: k = m1 = ks*32+q*8+j, n = b = bl*16+lr
        short8 b1[4][2];
        if constexpr (XBF) {
            const u16* xp = (const u16*)x_ +
                            (size_t)(bt * 64 + lr) * 4096 + m2 * 64 + q * 8;
            #pragma unroll
            for (int bl = 0; bl < 4; ++bl)
                #pragma unroll
                for (int ks = 0; ks < 2; ++ks)
                    b1[bl][ks] = *(const short8*)(xp + bl * 16 * 4096 + ks * 32);
        } else {
            const float* xp = (const float*)x_ +
                              (size_t)(bt * 64 + lr) * 4096 + m2 * 64 + q * 8;
            #pragma unroll
            for (int bl = 0; bl < 4; ++bl)
                #pragma unroll
                for (int ks = 0; ks < 2; ++ks) {
                    const float* p = xp + bl * 16 * 4096 + ks * 32;
                    float4 ua = *(const float4*)(p);
                    float4 ub = *(const float4*)(p + 4);
                    short8 r;
                    r[0] = (short)f2bf(ua.x); r[1] = (short)f2bf(ua.y);
                    r[2] = (short)f2bf(ua.z); r[3] = (short)f2bf(ua.w);
                    r[4] = (short)f2bf(ub.x); r[5] = (short)f2bf(ub.y);
                    r[6] = (short)f2bf(ub.z); r[7] = (short)f2bf(ub.w);
                    b1[bl][ks] = r;
                }
        }
        f32x4 acc1[2][4];
        #pragma unroll
        for (int ct = 0; ct < 2; ++ct)
            #pragma unroll
            for (int bl = 0; bl < 4; ++bl) acc1[ct][bl] = fz;
        #pragma unroll
        for (int ks = 0; ks < 2; ++ks)
            #pragma unroll
            for (int ct = 0; ct < 2; ++ct)
                #pragma unroll
                for (int bl = 0; bl < 4; ++bl)
                    acc1[ct][bl] = MFMA16(a1[ct][ks], b1[bl][ks], acc1[ct][bl]);

        __syncthreads();   // prior iteration's stage-2 LDS reads done

        // tT -> t_lds[b][w*32+c']; D: row = c' = ct*16+q*4+g, col = b = bl*16+lr
        #pragma unroll
        for (int ct = 0; ct < 2; ++ct)
            #pragma unroll
            for (int bl = 0; bl < 4; ++bl) {
                int off = (bl * 16 + lr) * 260 + w * 32 + ct * 16 + q * 4;
                u32 lo = (u32)f2bf(acc1[ct][bl][0]) | ((u32)f2bf(acc1[ct][bl][1]) << 16);
                u32 hi = (u32)f2bf(acc1[ct][bl][2]) | ((u32)f2bf(acc1[ct][bl][3]) << 16);
                *(uint2*)(&t_lds[off]) = make_uint2(lo, hi);
            }

        __syncthreads();   // all t written before stage-2 reads

        // ---- stage 2: y[b][n2] += t2(64x32) . W2T_slice(32x64) ----
        short8 a2[4];
        #pragma unroll
        for (int bl = 0; bl < 4; ++bl) {
            int base = (bl * 16 + lr) * 260 + (2 * q) * 32 + w * 4;
            union { short8 v; uint2 u[2]; } tmp;
            tmp.u[0] = *(const uint2*)(&t_lds[base]);
            tmp.u[1] = *(const uint2*)(&t_lds[base + 32]);
            a2[bl] = tmp.v;
        }
        short8 b2[4];
        {
            const u16* w2p = W2T + n1 * 16384 + lr * 256 + m2b * 32 + q * 8;
            #pragma unroll
            for (int nt = 0; nt < 4; ++nt)
                b2[nt] = *(const short8*)(w2p + nt * (16 * 256));
        }
        #pragma unroll
        for (int bl = 0; bl < 4; ++bl)
            #pragma unroll
            for (int nt = 0; nt < 4; ++nt)
                acc2[bl][nt] = MFMA16(a2[bl], b2[nt], acc2[bl][nt]);
    }

    // ---- epilogue: D rows = b (q*4+g), cols = n2 (lr); fp32 stores ----
    #pragma unroll
    for (int bl = 0; bl < 4; ++bl)
        #pragma unroll
        for (int nt = 0; nt < 4; ++nt)
            #pragma unroll
            for (int g = 0; g < 4; ++g) {
                long row = bt * 64 + bl * 16 + q * 4 + g;
                long col = (long)n1 * 64 + nt * 16 + lr;
                out[row * 4096 + col] = acc2[bl][nt][g];
            }
}

// ---------------------------------------------------------------------------
// Fallback (no workspace): scalar weight loads from natural layouts.
// Round-2 HW-proven. Used only if ws_size < 4 MB.
// ---------------------------------------------------------------------------
__global__ __launch_bounds__(512) void btt_nows(const float* __restrict__ x,
                                                const float* __restrict__ W1,
                                                const float* __restrict__ W2,
                                                float* __restrict__ out) {
    __shared__ u16 t_lds[64 * 260];
    const int tid = threadIdx.x;
    const int w = tid >> 6;
    const int lane = tid & 63;
    const int q = lane >> 4;
    const int lr = lane & 15;
    const int bt = blockIdx.x & 63;
    const int nb = blockIdx.x >> 6;
    const int n1 = nb * 8 + w;

    const f32x4 fz = {0.f, 0.f, 0.f, 0.f};
    f32x4 acc2[4][4];
    #pragma unroll
    for (int i = 0; i < 4; ++i)
        #pragma unroll
        for (int j = 0; j < 4; ++j) acc2[i][j] = fz;

    for (int m2b = 0; m2b < 8; ++m2b) {
        const int m2 = m2b * 8 + w;
        short8 ax[4][2];
        #pragma unroll
        for (int bl = 0; bl < 4; ++bl)
            #pragma unroll
            for (int ks = 0; ks < 2; ++ks) {
                const float* p = x + (size_t)(bt * 64 + bl * 16 + lr) * 4096 +
                                 m2 * 64 + ks * 32 + q * 8;
                float4 ua = *(const float4*)(p);
                float4 ub = *(const float4*)(p + 4);
                short8 r;
                r[0] = (short)f2bf(ua.x); r[1] = (short)f2bf(ua.y);
                r[2] = (short)f2bf(ua.z); r[3] = (short)f2bf(ua.w);
                r[4] = (short)f2bf(ub.x); r[5] = (short)f2bf(ub.y);
                r[6] = (short)f2bf(ub.z); r[7] = (short)f2bf(ub.w);
                ax[bl][ks] = r;
            }
        short8 bw1[2][2];
        #pragma unroll
        for (int ct = 0; ct < 2; ++ct)
            #pragma unroll
            for (int ks = 0; ks < 2; ++ks)
                #pragma unroll
                for (int j = 0; j < 8; ++j)
                    bw1[ct][ks][j] = (short)f2bf(W1[m2 * 16384 +
                                                    (ks * 32 + q * 8 + j) * 256 +
                                                    nb * 32 + ct * 16 + lr]);
        f32x4 acc1[4][2];
        #pragma unroll
        for (int bl = 0; bl < 4; ++bl)
            #pragma unroll
            for (int ct = 0; ct < 2; ++ct) acc1[bl][ct] = fz;
        #pragma unroll
        for (int ks = 0; ks < 2; ++ks)
            #pragma unroll
            for (int bl = 0; bl < 4; ++bl)
                #pragma unroll
                for (int ct = 0; ct < 2; ++ct)
                    acc1[bl][ct] = MFMA16(ax[bl][ks], bw1[ct][ks], acc1[bl][ct]);

        __syncthreads();
        #pragma unroll
        for (int bl = 0; bl < 4; ++bl)
            #pragma unroll
            for (int ct = 0; ct < 2; ++ct)
                #pragma unroll
                for (int g = 0; g < 4; ++g)
                    t_lds[(bl * 16 + q * 4 + g) * 260 + w * 32 + ct * 16 + lr] =
                        f2bf(acc1[bl][ct][g]);
        __syncthreads();

        short8 a2[4];
        #pragma unroll
        for (int bl = 0; bl < 4; ++bl) {
            int base = (bl * 16 + lr) * 260 + (2 * q) * 32 + w * 4;
            union { short8 v; uint2 u[2]; } tmp;
            tmp.u[0] = *(const uint2*)(&t_lds[base]);
            tmp.u[1] = *(const uint2*)(&t_lds[base + 32]);
            a2[bl] = tmp.v;
        }
        short8 b2[4];
        #pragma unroll
        for (int nt = 0; nt < 4; ++nt)
            #pragma unroll
            for (int j = 0; j < 8; ++j)
                b2[nt][j] = (short)f2bf(W2[n1 * 16384 +
                                           (m2b * 32 + q * 8 + j) * 64 +
                                           nt * 16 + lr]);
        #pragma unroll
        for (int bl = 0; bl < 4; ++bl)
            #pragma unroll
            for (int nt = 0; nt < 4; ++nt)
                acc2[bl][nt] = MFMA16(a2[bl], b2[nt], acc2[bl][nt]);
    }

    #pragma unroll
    for (int bl = 0; bl < 4; ++bl)
        #pragma unroll
        for (int nt = 0; nt < 4; ++nt)
            #pragma unroll
            for (int g = 0; g < 4; ++g) {
                long row = bt * 64 + bl * 16 + q * 4 + g;
                long col = (long)n1 * 64 + nt * 16 + lr;
                out[row * 4096 + col] = acc2[bl][nt][g];
            }
}

extern "C" void kernel_launch(void* const* d_in, const int* in_sizes, int n_in,
                              void* d_out, int out_size, void* d_ws, size_t ws_size,
                              hipStream_t stream) {
    const float* x  = (const float*)d_in[0];   // (4096, 4096) fp32
    const float* W1 = (const float*)d_in[1];   // (64, 64, 256) fp32
    const float* W2 = (const float*)d_in[2];   // (64, 256, 64) fp32
    float* out = (float*)d_out;

    const size_t WS_W  = 2u * 64 * 256 * 64 * sizeof(u16);          // 4 MB weights
    const size_t WS_X  = (size_t)4096 * 4096 * sizeof(u16);         // 32 MB x bf16
    u16* W1T = (u16*)d_ws;                 // (64, 256, 64) bf16
    u16* W2T = W1T + 64 * 256 * 64;        // (64, 64, 256) bf16
    u16* XB  = W2T + 64 * 64 * 256;        // (4096, 4096) bf16

    if (ws_size >= WS_W + WS_X) {
        transpose_cvt<64, 256, 16><<<64 * 4, 256, 0, stream>>>(W1, W1T);
        transpose_cvt<256, 64, 64><<<64 * 4, 256, 0, stream>>>(W2, W2T);
        cvt_x<<<4096 * 4096 / (256 * 8), 256, 0, stream>>>(x, XB);
        btt_main<true><<<512, 512, 0, stream>>>(XB, W1T, W2T, out);
    } else if (ws_size >= WS_W) {
        transpose_cvt<64, 256, 16><<<64 * 4, 256, 0, stream>>>(W1, W1T);
        transpose_cvt<256, 64, 64><<<64 * 4, 256, 0, stream>>>(W2, W2T);
        btt_main<false><<<512, 512, 0, stream>>>(x, W1T, W2T, out);
    } else {
        btt_nows<<<512, 512, 0, stream>>>(x, W1, W2, out);
    }
}

// Round 5
// 166.003 us; speedup vs baseline: 1.8200x; 1.1692x over previous
//
#include <hip/hip_runtime.h>

typedef unsigned short u16;
typedef unsigned int u32;
typedef __attribute__((ext_vector_type(8))) short short8;
typedef __attribute__((ext_vector_type(4))) float f32x4;

__device__ __forceinline__ u16 f2bf(float f) {
    union { float f; u32 u; } c; c.f = f;
    u32 u = c.u;
    return (u16)((u + 0x7fffu + ((u >> 16) & 1u)) >> 16);
}

#define MFMA16(A, B, C) __builtin_amdgcn_mfma_f32_16x16x32_bf16((A), (B), (C), 0, 0, 0)

// ---------------------------------------------------------------------------
// Unified prepass: emit x / W1 / W2 in FRAGMENT-MAJOR bf16 layouts so every
// hot-loop load in btt_main is `base + lane*16` (fully coalesced).
//   XF  [bt][m2][bl][ks][lane][8] : x[bt*64+bl*16+lr][m2*64+ks*32+q*8+j]
//   W1F [m2][nb][ct][ks][lane][8] : W1[m2][m1=ks*32+q*8+j][c=nb*32+ct*16+lr]
//   W2F [n1][m2b][nt][lane][8]    : W2[n1][k=m2b*32+q*8+j][n2=nt*16+lr]
// (lane = q*16+lr).  Grid: 4096 XF blocks + 64 W1F + 64 W2F, 256 thr.
// ---------------------------------------------------------------------------
__global__ __launch_bounds__(256) void prep_all(const float* __restrict__ x,
                                                const float* __restrict__ W1,
                                                const float* __restrict__ W2,
                                                u16* __restrict__ W1F,
                                                u16* __restrict__ W2F,
                                                u16* __restrict__ XF) {
    __shared__ u16 sh[16384];
    const int bid = blockIdx.x;
    const int t = threadIdx.x;

    if (bid < 4096) {
        // ---- XF: tile (bt, m2) = 64 rows x 64 cols, 8 KB out ----
        const int bt = bid >> 6, m2 = bid & 63;
        const int r = t >> 2, lr = r & 15, bl = r >> 4;
        const int c0 = (t & 3) * 16;
        const float* src = x + ((size_t)bt * 64 + r) * 4096 + m2 * 64 + c0;
        float4 f[4];
        #pragma unroll
        for (int s = 0; s < 4; ++s) f[s] = ((const float4*)src)[s];
        u16 v[16];
        #pragma unroll
        for (int s = 0; s < 4; ++s) {
            v[s * 4 + 0] = f2bf(f[s].x); v[s * 4 + 1] = f2bf(f[s].y);
            v[s * 4 + 2] = f2bf(f[s].z); v[s * 4 + 3] = f2bf(f[s].w);
        }
        #pragma unroll
        for (int h = 0; h < 2; ++h) {
            int cc = (t & 3) * 2 + h;          // chunk of 8 cols
            int ks = cc >> 2, q = cc & 3;
            int off = (((bl * 2 + ks) * 4 + q) << 7) + lr * 8;
            short8 pk;
            #pragma unroll
            for (int j = 0; j < 8; ++j) pk[j] = (short)v[h * 8 + j];
            *(short8*)(&sh[off]) = pk;
        }
        __syncthreads();
        u16* dst = XF + (size_t)bid * 4096 + t * 16;
        *(short8*)(dst) = *(const short8*)(&sh[t * 16]);
        *(short8*)(dst + 8) = *(const short8*)(&sh[t * 16 + 8]);
    } else if (bid < 4160) {
        // ---- W1F: one m2 slice (64 x 256 fp32 -> 32 KB bf16) ----
        const int m2 = bid - 4096;
        const float* src = W1 + (size_t)m2 * 16384 + t * 64;
        #pragma unroll
        for (int s = 0; s < 16; ++s) {
            float4 f = ((const float4*)src)[s];
            float fv[4] = {f.x, f.y, f.z, f.w};
            #pragma unroll
            for (int e = 0; e < 4; ++e) {
                int elem = t * 64 + s * 4 + e;
                int m1 = elem >> 8, c = elem & 255;
                int nb = c >> 5, ct = (c >> 4) & 1, lr = c & 15;
                int ks = m1 >> 5, q = (m1 >> 3) & 3, j = m1 & 7;
                sh[(((((nb * 2 + ct) * 2 + ks) * 4 + q)) << 7) + lr * 8 + j] =
                    f2bf(fv[e]);
            }
        }
        __syncthreads();
        u16* dst = W1F + (size_t)m2 * 16384 + t * 64;
        #pragma unroll
        for (int s = 0; s < 8; ++s)
            *(short8*)(dst + s * 8) = *(const short8*)(&sh[t * 64 + s * 8]);
    } else {
        // ---- W2F: one n1 slice (256 x 64 fp32 -> 32 KB bf16) ----
        const int n1 = bid - 4160;
        const float* src = W2 + (size_t)n1 * 16384 + t * 64;
        #pragma unroll
        for (int s = 0; s < 16; ++s) {
            float4 f = ((const float4*)src)[s];
            float fv[4] = {f.x, f.y, f.z, f.w};
            #pragma unroll
            for (int e = 0; e < 4; ++e) {
                int elem = t * 64 + s * 4 + e;
                int k = elem >> 6, n2 = elem & 63;
                int m2b = k >> 5, q = (k >> 3) & 3, j = k & 7;
                int nt = n2 >> 4, lr = n2 & 15;
                sh[((((m2b * 4 + nt) * 4 + q)) << 7) + lr * 8 + j] = f2bf(fv[e]);
            }
        }
        __syncthreads();
        u16* dst = W2F + (size_t)n1 * 16384 + t * 64;
        #pragma unroll
        for (int s = 0; s < 8; ++s)
            *(short8*)(dst + s * 8) = *(const short8*)(&sh[t * 64 + s * 8]);
    }
}

// ---------------------------------------------------------------------------
// Fused BTT main kernel — all global loads fragment-major coalesced
// (base + lane*16). Math core, t-LDS round trip, XCD mapping identical to the
// round-4 HW-proven kernel.
// Block mapping bt = blockIdx&63, nb = blockIdx>>6: the 8 nb-blocks sharing an
// x-tile land on the same XCD (round-3-measured: 49 MB fetch vs 300 flipped).
// MFMA 16x16x32 bf16: A[m=lane&15][k=q*8+j], B[k=q*8+j][n=lane&15],
//                     D[row=q*4+reg][col=lane&15]  (m89/m91-verified).
// ---------------------------------------------------------------------------
__global__ __launch_bounds__(512) void btt_main(const u16* __restrict__ XF,
                                                const u16* __restrict__ W1F,
                                                const u16* __restrict__ W2F,
                                                float* __restrict__ out) {
    __shared__ u16 t_lds[64 * 260];

    const int tid = threadIdx.x;
    const int w = tid >> 6;       // wave 0..7
    const int lane = tid & 63;
    const int q = lane >> 4;      // quad
    const int lr = lane & 15;
    const int bt = blockIdx.x & 63;
    const int nb = blockIdx.x >> 6;
    const int n1 = nb * 8 + w;

    const f32x4 fz = {0.f, 0.f, 0.f, 0.f};
    f32x4 acc2[4][4];             // y[b(4x16)][n2(4x16)]
    #pragma unroll
    for (int i = 0; i < 4; ++i)
        #pragma unroll
        for (int j = 0; j < 4; ++j) acc2[i][j] = fz;

    for (int m2b = 0; m2b < 8; ++m2b) {
        const int m2 = m2b * 8 + w;

        // ---- stage 1: tT[c'(32)][b(64)] = W1_slice(32x64) . xT(64x64) ----
        short8 a1[2][2];
        {
            const u16* p = W1F + ((size_t)m2 * 8 + nb) * 2048 + lane * 8;
            #pragma unroll
            for (int ct = 0; ct < 2; ++ct)
                #pragma unroll
                for (int ks = 0; ks < 2; ++ks)
                    a1[ct][ks] = *(const short8*)(p + (ct * 2 + ks) * 512);
        }
        short8 b1[4][2];
        {
            const u16* p = XF + ((size_t)bt * 64 + m2) * 4096 + lane * 8;
            #pragma unroll
            for (int bl = 0; bl < 4; ++bl)
                #pragma unroll
                for (int ks = 0; ks < 2; ++ks)
                    b1[bl][ks] = *(const short8*)(p + (bl * 2 + ks) * 512);
        }
        f32x4 acc1[2][4];
        #pragma unroll
        for (int ct = 0; ct < 2; ++ct)
            #pragma unroll
            for (int bl = 0; bl < 4; ++bl) acc1[ct][bl] = fz;
        #pragma unroll
        for (int ks = 0; ks < 2; ++ks)
            #pragma unroll
            for (int ct = 0; ct < 2; ++ct)
                #pragma unroll
                for (int bl = 0; bl < 4; ++bl)
                    acc1[ct][bl] = MFMA16(a1[ct][ks], b1[bl][ks], acc1[ct][bl]);

        __syncthreads();   // prior iteration's stage-2 LDS reads done

        // tT -> t_lds[b][w*32+c']; D: row = c' = ct*16+q*4+g, col = b = bl*16+lr
        #pragma unroll
        for (int ct = 0; ct < 2; ++ct)
            #pragma unroll
            for (int bl = 0; bl < 4; ++bl) {
                int off = (bl * 16 + lr) * 260 + w * 32 + ct * 16 + q * 4;
                u32 lo = (u32)f2bf(acc1[ct][bl][0]) | ((u32)f2bf(acc1[ct][bl][1]) << 16);
                u32 hi = (u32)f2bf(acc1[ct][bl][2]) | ((u32)f2bf(acc1[ct][bl][3]) << 16);
                *(uint2*)(&t_lds[off]) = make_uint2(lo, hi);
            }

        __syncthreads();   // all t written before stage-2 reads

        // ---- stage 2: y[b][n2] += t2(64x32) . W2_slice(32x64) ----
        short8 a2[4];
        #pragma unroll
        for (int bl = 0; bl < 4; ++bl) {
            int base = (bl * 16 + lr) * 260 + (2 * q) * 32 + w * 4;
            union { short8 v; uint2 u[2]; } tmp;
            tmp.u[0] = *(const uint2*)(&t_lds[base]);
            tmp.u[1] = *(const uint2*)(&t_lds[base + 32]);
            a2[bl] = tmp.v;
        }
        short8 b2[4];
        {
            const u16* p = W2F + (size_t)n1 * 16384 + m2b * 2048 + lane * 8;
            #pragma unroll
            for (int nt = 0; nt < 4; ++nt)
                b2[nt] = *(const short8*)(p + nt * 512);
        }
        #pragma unroll
        for (int bl = 0; bl < 4; ++bl)
            #pragma unroll
            for (int nt = 0; nt < 4; ++nt)
                acc2[bl][nt] = MFMA16(a2[bl], b2[nt], acc2[bl][nt]);
    }

    // ---- epilogue: D rows = b (q*4+g), cols = n2 (lr); fp32 stores ----
    #pragma unroll
    for (int bl = 0; bl < 4; ++bl)
        #pragma unroll
        for (int nt = 0; nt < 4; ++nt)
            #pragma unroll
            for (int g = 0; g < 4; ++g) {
                long row = bt * 64 + bl * 16 + q * 4 + g;
                long col = (long)n1 * 64 + nt * 16 + lr;
                out[row * 4096 + col] = acc2[bl][nt][g];
            }
}

// ---------------------------------------------------------------------------
// Fallback (ws too small): round-2 HW-proven scalar-weight-load kernel.
// ---------------------------------------------------------------------------
__global__ __launch_bounds__(512) void btt_nows(const float* __restrict__ x,
                                                const float* __restrict__ W1,
                                                const float* __restrict__ W2,
                                                float* __restrict__ out) {
    __shared__ u16 t_lds[64 * 260];
    const int tid = threadIdx.x;
    const int w = tid >> 6;
    const int lane = tid & 63;
    const int q = lane >> 4;
    const int lr = lane & 15;
    const int bt = blockIdx.x & 63;
    const int nb = blockIdx.x >> 6;
    const int n1 = nb * 8 + w;

    const f32x4 fz = {0.f, 0.f, 0.f, 0.f};
    f32x4 acc2[4][4];
    #pragma unroll
    for (int i = 0; i < 4; ++i)
        #pragma unroll
        for (int j = 0; j < 4; ++j) acc2[i][j] = fz;

    for (int m2b = 0; m2b < 8; ++m2b) {
        const int m2 = m2b * 8 + w;
        short8 ax[4][2];
        #pragma unroll
        for (int bl = 0; bl < 4; ++bl)
            #pragma unroll
            for (int ks = 0; ks < 2; ++ks) {
                const float* p = x + (size_t)(bt * 64 + bl * 16 + lr) * 4096 +
                                 m2 * 64 + ks * 32 + q * 8;
                float4 ua = *(const float4*)(p);
                float4 ub = *(const float4*)(p + 4);
                short8 r;
                r[0] = (short)f2bf(ua.x); r[1] = (short)f2bf(ua.y);
                r[2] = (short)f2bf(ua.z); r[3] = (short)f2bf(ua.w);
                r[4] = (short)f2bf(ub.x); r[5] = (short)f2bf(ub.y);
                r[6] = (short)f2bf(ub.z); r[7] = (short)f2bf(ub.w);
                ax[bl][ks] = r;
            }
        short8 bw1[2][2];
        #pragma unroll
        for (int ct = 0; ct < 2; ++ct)
            #pragma unroll
            for (int ks = 0; ks < 2; ++ks)
                #pragma unroll
                for (int j = 0; j < 8; ++j)
                    bw1[ct][ks][j] = (short)f2bf(W1[m2 * 16384 +
                                                    (ks * 32 + q * 8 + j) * 256 +
                                                    nb * 32 + ct * 16 + lr]);
        f32x4 acc1[4][2];
        #pragma unroll
        for (int bl = 0; bl < 4; ++bl)
            #pragma unroll
            for (int ct = 0; ct < 2; ++ct) acc1[bl][ct] = fz;
        #pragma unroll
        for (int ks = 0; ks < 2; ++ks)
            #pragma unroll
            for (int bl = 0; bl < 4; ++bl)
                #pragma unroll
                for (int ct = 0; ct < 2; ++ct)
                    acc1[bl][ct] = MFMA16(ax[bl][ks], bw1[ct][ks], acc1[bl][ct]);

        __syncthreads();
        #pragma unroll
        for (int bl = 0; bl < 4; ++bl)
            #pragma unroll
            for (int ct = 0; ct < 2; ++ct)
                #pragma unroll
                for (int g = 0; g < 4; ++g)
                    t_lds[(bl * 16 + q * 4 + g) * 260 + w * 32 + ct * 16 + lr] =
                        f2bf(acc1[bl][ct][g]);
        __syncthreads();

        short8 a2[4];
        #pragma unroll
        for (int bl = 0; bl < 4; ++bl) {
            int base = (bl * 16 + lr) * 260 + (2 * q) * 32 + w * 4;
            union { short8 v; uint2 u[2]; } tmp;
            tmp.u[0] = *(const uint2*)(&t_lds[base]);
            tmp.u[1] = *(const uint2*)(&t_lds[base + 32]);
            a2[bl] = tmp.v;
        }
        short8 b2[4];
        #pragma unroll
        for (int nt = 0; nt < 4; ++nt)
            #pragma unroll
            for (int j = 0; j < 8; ++j)
                b2[nt][j] = (short)f2bf(W2[n1 * 16384 +
                                           (m2b * 32 + q * 8 + j) * 64 +
                                           nt * 16 + lr]);
        #pragma unroll
        for (int bl = 0; bl < 4; ++bl)
            #pragma unroll
            for (int nt = 0; nt < 4; ++nt)
                acc2[bl][nt] = MFMA16(a2[bl], b2[nt], acc2[bl][nt]);
    }

    #pragma unroll
    for (int bl = 0; bl < 4; ++bl)
        #pragma unroll
        for (int nt = 0; nt < 4; ++nt)
            #pragma unroll
            for (int g = 0; g < 4; ++g) {
                long row = bt * 64 + bl * 16 + q * 4 + g;
                long col = (long)n1 * 64 + nt * 16 + lr;
                out[row * 4096 + col] = acc2[bl][nt][g];
            }
}

extern "C" void kernel_launch(void* const* d_in, const int* in_sizes, int n_in,
                              void* d_out, int out_size, void* d_ws, size_t ws_size,
                              hipStream_t stream) {
    const float* x  = (const float*)d_in[0];   // (4096, 4096) fp32
    const float* W1 = (const float*)d_in[1];   // (64, 64, 256) fp32
    const float* W2 = (const float*)d_in[2];   // (64, 256, 64) fp32
    float* out = (float*)d_out;

    const size_t N_W1F = (size_t)64 * 16384;          // 1M elems, 2 MiB
    const size_t N_W2F = (size_t)64 * 16384;          // 2 MiB
    const size_t N_XF  = (size_t)4096 * 4096;         // 32 MiB
    const size_t WS_NEED = (N_W1F + N_W2F + N_XF) * sizeof(u16);  // 36 MiB

    if (ws_size >= WS_NEED) {
        u16* W1F = (u16*)d_ws;
        u16* W2F = W1F + N_W1F;
        u16* XF  = W2F + N_W2F;
        prep_all<<<4096 + 64 + 64, 256, 0, stream>>>(x, W1, W2, W1F, W2F, XF);
        btt_main<<<512, 512, 0, stream>>>(XF, W1F, W2F, out);
    } else {
        btt_nows<<<512, 512, 0, stream>>>(x, W1, W2, out);
    }
}